// Round 9
// baseline (329.625 us; speedup 1.0000x reference)
//
#include <hip/hip_runtime.h>

#define S_LEN 2048
#define NH    16
#define HD    64
#define HID   1024
#define BATCH 2

typedef __bf16 bf16x8 __attribute__((ext_vector_type(8)));
typedef float  f32x4  __attribute__((ext_vector_type(4)));

__device__ __forceinline__ unsigned short f2bf(float f) {
    unsigned int u = __float_as_uint(f);
    u += 0x7fffu + ((u >> 16) & 1u);           // RNE
    return (unsigned short)(u >> 16);
}
__device__ __forceinline__ unsigned int pk2(float lo, float hi) {
    return (unsigned int)f2bf(lo) | ((unsigned int)f2bf(hi) << 16);
}
__device__ __forceinline__ uint4 pk8(float4 a, float4 b) {
    uint4 o;
    o.x = pk2(a.x, a.y); o.y = pk2(a.z, a.w);
    o.z = pk2(b.x, b.y); o.w = pk2(b.z, b.w);
    return o;
}

__global__ __launch_bounds__(256)
void fill_constf(float* __restrict__ out, long n, float v) {
    long i = (long)blockIdx.x * 256 + threadIdx.x;
    const long stride = (long)gridDim.x * 256;
    for (; i < n; i += stride) out[i] = v;
}

// C = A[M,K] @ W[N,K]^T + bias.  W fp32; A fp32 (AF32) or bf16.
// mode 0: scatter bf16 to q/k/v^T ws buffers (N=3072); mode 1: fp32 row-major store.
template<bool AF32>
__global__ __launch_bounds__(256)
void fused_gemm(const void* __restrict__ Aptr,
                const float* __restrict__ W,
                const float* __restrict__ bias,
                unsigned short* __restrict__ o0,
                unsigned short* __restrict__ o1,
                unsigned short* __restrict__ o2,
                float* __restrict__ of,
                int mode)
{
    __shared__ __align__(16) unsigned short lA[128 * 40];
    __shared__ __align__(16) unsigned short lB[128 * 40];
    const int tid  = threadIdx.x;
    const int lane = tid & 63, wv = tid >> 6;
    const int quad = lane >> 4, l16 = lane & 15;
    const int wm = (wv & 1) * 64, wn = (wv >> 1) * 64;
    const int m0 = blockIdx.y * 128, n0 = blockIdx.x * 128;
    const int K = HID;

    f32x4 acc[4][4] = {};

    const int ar = tid >> 2, ac = (tid & 3) * 8;

    for (int k0 = 0; k0 < K; k0 += 32) {
        if (AF32) {
            const float* Af = (const float*)Aptr;
            const float* p0 = Af + (long)(m0 + ar) * K + k0 + ac;
            const float* p1 = Af + (long)(m0 + ar + 64) * K + k0 + ac;
            *(uint4*)&lA[ar * 40 + ac]        = pk8(*(const float4*)p0, *(const float4*)(p0 + 4));
            *(uint4*)&lA[(ar + 64) * 40 + ac] = pk8(*(const float4*)p1, *(const float4*)(p1 + 4));
        } else {
            const unsigned short* Ab = (const unsigned short*)Aptr;
            *(uint4*)&lA[ar * 40 + ac]        = *(const uint4*)(Ab + (long)(m0 + ar) * K + k0 + ac);
            *(uint4*)&lA[(ar + 64) * 40 + ac] = *(const uint4*)(Ab + (long)(m0 + ar + 64) * K + k0 + ac);
        }
        {
            const float* q0 = W + (long)(n0 + ar) * K + k0 + ac;
            const float* q1 = W + (long)(n0 + ar + 64) * K + k0 + ac;
            *(uint4*)&lB[ar * 40 + ac]        = pk8(*(const float4*)q0, *(const float4*)(q0 + 4));
            *(uint4*)&lB[(ar + 64) * 40 + ac] = pk8(*(const float4*)q1, *(const float4*)(q1 + 4));
        }
        __syncthreads();

        bf16x8 af[4], bfr[4];
#pragma unroll
        for (int mt = 0; mt < 4; mt++)
            af[mt] = *(const bf16x8*)&lA[(wm + mt * 16 + l16) * 40 + quad * 8];
#pragma unroll
        for (int nt = 0; nt < 4; nt++)
            bfr[nt] = *(const bf16x8*)&lB[(wn + nt * 16 + l16) * 40 + quad * 8];
#pragma unroll
        for (int mt = 0; mt < 4; mt++)
#pragma unroll
            for (int nt = 0; nt < 4; nt++)
                acc[mt][nt] = __builtin_amdgcn_mfma_f32_16x16x32_bf16(
                    af[mt], bfr[nt], acc[mt][nt], 0, 0, 0);
        __syncthreads();
    }

    if (mode == 0) {
#pragma unroll
        for (int nt = 0; nt < 4; nt++) {
            const int n = n0 + wn + nt * 16 + l16;
            const float bv = bias[n];
            const int part = n >> 10, f = n & 1023, h = f >> 6, d = f & 63;
#pragma unroll
            for (int mt = 0; mt < 4; mt++) {
                const int mbase = m0 + wm + mt * 16 + quad * 4;
#pragma unroll
                for (int r = 0; r < 4; r++) {
                    const int m = mbase + r;
                    const int b = m >> 11, s = m & 2047;
                    const unsigned short o = f2bf(acc[mt][nt][r] + bv);
                    const int bh = b * NH + h;
                    if (part == 0)      o0[((long)bh * S_LEN + s) * HD + d] = o;
                    else if (part == 1) o1[((long)bh * S_LEN + s) * HD + d] = o;
                    else                o2[((long)bh * HD + d) * S_LEN + s] = o;
                }
            }
        }
    } else {
        // FP32 output store (the round-8 fix: harness output buffer is fp32)
#pragma unroll
        for (int nt = 0; nt < 4; nt++) {
            const int n = n0 + wn + nt * 16 + l16;
            const float bv = bias[n];
#pragma unroll
            for (int mt = 0; mt < 4; mt++) {
                const int mbase = m0 + wm + mt * 16 + quad * 4;
#pragma unroll
                for (int r = 0; r < 4; r++) {
                    const int m = mbase + r;
                    of[(long)m * HID + n] = acc[mt][nt][r] + bv;
                }
            }
        }
    }
}

// Flash attention. grid = (S/64, NH, B), block = 256 (4 waves, 16 q-rows each).
__global__ __launch_bounds__(256)
void attn(const unsigned short* __restrict__ q,
          const unsigned short* __restrict__ k,
          const unsigned short* __restrict__ vt_g,   // [b,h,64,S] (V^T)
          const int* __restrict__ mask,
          unsigned short* __restrict__ ctx)          // [b,S,1024] bf16
{
    __shared__ __align__(16) unsigned short kt[64 * 88];   // [key][d]
    __shared__ __align__(16) unsigned short vt[64 * 88];   // [d][key]
    __shared__ __align__(16) __bf16 pt[4][16 * 88];        // per-wave P tile [qrow][key]
    __shared__ float mkv[64];

    const int tid  = threadIdx.x;
    const int lane = tid & 63, wv = tid >> 6;
    const int quad = lane >> 4, l16 = lane & 15;
    const int qt = blockIdx.x, h = blockIdx.y, b = blockIdx.z;
    const int bh = b * NH + h;

    const int sq = qt * 64 + wv * 16 + l16;
    bf16x8 qf0 = *(const bf16x8*)&q[((long)bh * S_LEN + sq) * HD + quad * 8];
    bf16x8 qf1 = *(const bf16x8*)&q[((long)bh * S_LEN + sq) * HD + 32 + quad * 8];

    float mrun[4], lrun[4];
    f32x4 Of[4] = {};
#pragma unroll
    for (int r = 0; r < 4; r++) { mrun[r] = -1e30f; lrun[r] = 0.f; }

    const int r8 = tid >> 3, c8 = (tid & 7) * 8;
    __bf16* ptw = pt[wv];

    for (int k0 = 0; k0 < S_LEN; k0 += 64) {
        *(uint4*)&kt[r8 * 88 + c8]        = *(const uint4*)&k[((long)bh * S_LEN + k0 + r8) * HD + c8];
        *(uint4*)&kt[(r8 + 32) * 88 + c8] = *(const uint4*)&k[((long)bh * S_LEN + k0 + r8 + 32) * HD + c8];
        *(uint4*)&vt[r8 * 88 + c8]        = *(const uint4*)&vt_g[((long)bh * HD + r8) * S_LEN + k0 + c8];
        *(uint4*)&vt[(r8 + 32) * 88 + c8] = *(const uint4*)&vt_g[((long)bh * HD + r8 + 32) * S_LEN + k0 + c8];
        if (tid < 64) mkv[tid] = (mask[b * S_LEN + k0 + tid] == 0) ? -1e9f : 0.f;
        __syncthreads();

        float sv[4][4];
#pragma unroll
        for (int nt = 0; nt < 4; nt++) {
            bf16x8 b0 = *(const bf16x8*)&kt[(nt * 16 + l16) * 88 + quad * 8];
            bf16x8 b1 = *(const bf16x8*)&kt[(nt * 16 + l16) * 88 + 32 + quad * 8];
            f32x4 s = {};
            s = __builtin_amdgcn_mfma_f32_16x16x32_bf16(qf0, b0, s, 0, 0, 0);
            s = __builtin_amdgcn_mfma_f32_16x16x32_bf16(qf1, b1, s, 0, 0, 0);
            const float mv = mkv[nt * 16 + l16];
#pragma unroll
            for (int r = 0; r < 4; r++) sv[nt][r] = s[r] * 0.125f + mv;
        }

        float pr[4][4];
#pragma unroll
        for (int r = 0; r < 4; r++) {
            float rx = fmaxf(fmaxf(sv[0][r], sv[1][r]), fmaxf(sv[2][r], sv[3][r]));
#pragma unroll
            for (int off = 1; off < 16; off <<= 1) rx = fmaxf(rx, __shfl_xor(rx, off, 64));
            const float mn = fmaxf(mrun[r], rx);
            const float alpha = __expf(mrun[r] - mn);
            float rs = 0.f;
#pragma unroll
            for (int nt = 0; nt < 4; nt++) {
                float p = __expf(sv[nt][r] - mn);
                pr[nt][r] = p; rs += p;
            }
#pragma unroll
            for (int off = 1; off < 16; off <<= 1) rs += __shfl_xor(rs, off, 64);
            lrun[r] = lrun[r] * alpha + rs;
            mrun[r] = mn;
#pragma unroll
            for (int nt = 0; nt < 4; nt++) Of[nt][r] *= alpha;
        }

#pragma unroll
        for (int nt = 0; nt < 4; nt++)
#pragma unroll
            for (int r = 0; r < 4; r++)
                ptw[(quad * 4 + r) * 88 + nt * 16 + l16] = (__bf16)pr[nt][r];
        asm volatile("" ::: "memory");

#pragma unroll
        for (int ks = 0; ks < 2; ks++) {
            bf16x8 afp = *(const bf16x8*)&ptw[l16 * 88 + ks * 32 + quad * 8];
#pragma unroll
            for (int nt = 0; nt < 4; nt++) {
                bf16x8 bv = *(const bf16x8*)&vt[(nt * 16 + l16) * 88 + ks * 32 + quad * 8];
                Of[nt] = __builtin_amdgcn_mfma_f32_16x16x32_bf16(afp, bv, Of[nt], 0, 0, 0);
            }
        }
        __syncthreads();
    }

    float inv[4];
#pragma unroll
    for (int r = 0; r < 4; r++) inv[r] = 1.f / lrun[r];
#pragma unroll
    for (int nt = 0; nt < 4; nt++) {
        const int col = h * HD + nt * 16 + l16;
#pragma unroll
        for (int r = 0; r < 4; r++) {
            const int s = qt * 64 + wv * 16 + quad * 4 + r;
            ctx[((long)b * S_LEN + s) * HID + col] = f2bf(Of[nt][r] * inv[r]);
        }
    }
}

extern "C" void kernel_launch(void* const* d_in, const int* in_sizes, int n_in,
                              void* d_out, int out_size, void* d_ws, size_t ws_size,
                              hipStream_t stream) {
    float* outp = (float*)d_out;

    const float* x = nullptr; const int* mask = nullptr;
    const float* qkv_w = nullptr; const float* qkv_b = nullptr;
    const float* out_w = nullptr; const float* out_b = nullptr;
    for (int i = 0; i < n_in; i++) {
        switch (in_sizes[i]) {
            case 4194304: x     = (const float*)d_in[i]; break;
            case 4096:    mask  = (const int*)d_in[i];   break;
            case 3145728: qkv_w = (const float*)d_in[i]; break;
            case 3072:    qkv_b = (const float*)d_in[i]; break;
            case 1048576: out_w = (const float*)d_in[i]; break;
            case 1024:    out_b = (const float*)d_in[i]; break;
            default: break;
        }
    }
    if (!x || !mask || !qkv_w || !qkv_b || !out_w || !out_b) {
        fill_constf<<<256, 256, 0, stream>>>(outp, (long)out_size, 1000.0f);
        return;
    }

    const size_t per = (size_t)BATCH * NH * S_LEN * HD;   // 4,194,304 elements
    if (ws_size < 4 * per * sizeof(unsigned short)) {
        fill_constf<<<256, 256, 0, stream>>>(outp, (long)out_size, 2000.0f);
        return;
    }

    unsigned short* wsq = (unsigned short*)d_ws;
    unsigned short* wsk = wsq + per;
    unsigned short* wsv = wsk + per;   // V^T [b,h,64,S]
    unsigned short* wsc = wsv + per;   // ctx [b,S,1024] bf16

    fused_gemm<true><<<dim3(3 * HID / 128, BATCH * S_LEN / 128), 256, 0, stream>>>(
        x, qkv_w, qkv_b, wsq, wsk, wsv, nullptr, 0);
    attn<<<dim3(S_LEN / 64, NH, BATCH), 256, 0, stream>>>(wsq, wsk, wsv, mask, wsc);
    fused_gemm<false><<<dim3(HID / 128, BATCH * S_LEN / 128), 256, 0, stream>>>(
        wsc, out_w, out_b, nullptr, nullptr, nullptr, outp, 1);
}

// Round 10
// 267.723 us; speedup vs baseline: 1.2312x; 1.2312x over previous
//
#include <hip/hip_runtime.h>
#include <hip/hip_bf16.h>

#define S_LEN 2048
#define NH    16
#define HD    64
#define HID   1024
#define BATCH 2

typedef __bf16 bf16x8 __attribute__((ext_vector_type(8)));
typedef float  f32x4  __attribute__((ext_vector_type(4)));

__device__ __forceinline__ unsigned short f2bf(float f) {
    unsigned int u = __float_as_uint(f);
    u += 0x7fffu + ((u >> 16) & 1u);           // RNE
    return (unsigned short)(u >> 16);
}
__device__ __forceinline__ unsigned int pk2(float lo, float hi) {
    union { __hip_bfloat162 h; unsigned int u; } c;
    c.h = __float22bfloat162_rn(make_float2(lo, hi));   // v_cvt_pk_bf16_f32
    return c.u;
}
__device__ __forceinline__ uint4 pk8(float4 a, float4 b) {
    uint4 o;
    o.x = pk2(a.x, a.y); o.y = pk2(a.z, a.w);
    o.z = pk2(b.x, b.y); o.w = pk2(b.z, b.w);
    return o;
}

__global__ __launch_bounds__(256)
void fill_constf(float* __restrict__ out, long n, float v) {
    long i = (long)blockIdx.x * 256 + threadIdx.x;
    const long stride = (long)gridDim.x * 256;
    for (; i < n; i += stride) out[i] = v;
}

// fp32 -> bf16 bulk convert, 8 elems/thread-iter.
__global__ __launch_bounds__(256)
void cvt_bf16(const float* __restrict__ src, unsigned short* __restrict__ dst, long n8) {
    long t = (long)blockIdx.x * 256 + threadIdx.x;
    const long stride = (long)gridDim.x * 256;
    for (; t < n8; t += stride) {
        const float4 a = *(const float4*)(src + t * 8);
        const float4 b = *(const float4*)(src + t * 8 + 4);
        *(uint4*)(dst + t * 8) = pk8(a, b);
    }
}

// C = A[M,K] @ W[N,K]^T + bias (fp32 bias). A/W each fp32 or bf16 by template.
// mode 0: scatter bf16 to q/k/v^T ws buffers (N=3072); mode 1: fp32 row-major store.
template<bool AF32, bool WF32>
__global__ __launch_bounds__(256)
void fused_gemm(const void* __restrict__ Aptr,
                const void* __restrict__ Wptr,
                const float* __restrict__ bias,
                unsigned short* __restrict__ o0,
                unsigned short* __restrict__ o1,
                unsigned short* __restrict__ o2,
                float* __restrict__ of,
                int mode)
{
    __shared__ __align__(16) unsigned short lA[128 * 40];
    __shared__ __align__(16) unsigned short lB[128 * 40];
    const int tid  = threadIdx.x;
    const int lane = tid & 63, wv = tid >> 6;
    const int quad = lane >> 4, l16 = lane & 15;
    const int wm = (wv & 1) * 64, wn = (wv >> 1) * 64;
    const int m0 = blockIdx.y * 128, n0 = blockIdx.x * 128;
    const int K = HID;

    f32x4 acc[4][4] = {};
    const int ar = tid >> 2, ac = (tid & 3) * 8;

    for (int k0 = 0; k0 < K; k0 += 32) {
        if (AF32) {
            const float* Af = (const float*)Aptr;
            const float* p0 = Af + (long)(m0 + ar) * K + k0 + ac;
            const float* p1 = Af + (long)(m0 + ar + 64) * K + k0 + ac;
            *(uint4*)&lA[ar * 40 + ac]        = pk8(*(const float4*)p0, *(const float4*)(p0 + 4));
            *(uint4*)&lA[(ar + 64) * 40 + ac] = pk8(*(const float4*)p1, *(const float4*)(p1 + 4));
        } else {
            const unsigned short* Ab = (const unsigned short*)Aptr;
            *(uint4*)&lA[ar * 40 + ac]        = *(const uint4*)(Ab + (long)(m0 + ar) * K + k0 + ac);
            *(uint4*)&lA[(ar + 64) * 40 + ac] = *(const uint4*)(Ab + (long)(m0 + ar + 64) * K + k0 + ac);
        }
        if (WF32) {
            const float* Wf = (const float*)Wptr;
            const float* q0 = Wf + (long)(n0 + ar) * K + k0 + ac;
            const float* q1 = Wf + (long)(n0 + ar + 64) * K + k0 + ac;
            *(uint4*)&lB[ar * 40 + ac]        = pk8(*(const float4*)q0, *(const float4*)(q0 + 4));
            *(uint4*)&lB[(ar + 64) * 40 + ac] = pk8(*(const float4*)q1, *(const float4*)(q1 + 4));
        } else {
            const unsigned short* Wb = (const unsigned short*)Wptr;
            *(uint4*)&lB[ar * 40 + ac]        = *(const uint4*)(Wb + (long)(n0 + ar) * K + k0 + ac);
            *(uint4*)&lB[(ar + 64) * 40 + ac] = *(const uint4*)(Wb + (long)(n0 + ar + 64) * K + k0 + ac);
        }
        __syncthreads();

        bf16x8 af[4], bfr[4];
#pragma unroll
        for (int mt = 0; mt < 4; mt++)
            af[mt] = *(const bf16x8*)&lA[(wm + mt * 16 + l16) * 40 + quad * 8];
#pragma unroll
        for (int nt = 0; nt < 4; nt++)
            bfr[nt] = *(const bf16x8*)&lB[(wn + nt * 16 + l16) * 40 + quad * 8];
#pragma unroll
        for (int mt = 0; mt < 4; mt++)
#pragma unroll
            for (int nt = 0; nt < 4; nt++)
                acc[mt][nt] = __builtin_amdgcn_mfma_f32_16x16x32_bf16(
                    af[mt], bfr[nt], acc[mt][nt], 0, 0, 0);
        __syncthreads();
    }

    if (mode == 0) {
#pragma unroll
        for (int nt = 0; nt < 4; nt++) {
            const int n = n0 + wn + nt * 16 + l16;
            const float bv = bias[n];
            const int part = n >> 10, f = n & 1023, h = f >> 6, d = f & 63;
#pragma unroll
            for (int mt = 0; mt < 4; mt++) {
                const int mbase = m0 + wm + mt * 16 + quad * 4;
#pragma unroll
                for (int r = 0; r < 4; r++) {
                    const int m = mbase + r;
                    const int b = m >> 11, s = m & 2047;
                    const unsigned short o = f2bf(acc[mt][nt][r] + bv);
                    const int bh = b * NH + h;
                    if (part == 0)      o0[((long)bh * S_LEN + s) * HD + d] = o;
                    else if (part == 1) o1[((long)bh * S_LEN + s) * HD + d] = o;
                    else                o2[((long)bh * HD + d) * S_LEN + s] = o;
                }
            }
        }
    } else {
#pragma unroll
        for (int nt = 0; nt < 4; nt++) {
            const int n = n0 + wn + nt * 16 + l16;
            const float bv = bias[n];
#pragma unroll
            for (int mt = 0; mt < 4; mt++) {
                const int mbase = m0 + wm + mt * 16 + quad * 4;
#pragma unroll
                for (int r = 0; r < 4; r++) {
                    const int m = mbase + r;
                    of[(long)m * HID + n] = acc[mt][nt][r] + bv;
                }
            }
        }
    }
}

// Flash attention, S^T formulation. grid = (S/64, NH, B), block = 256.
// S^T = K·Q^T  (C-layout: col=q=l16, row=key=quad*4+r+16nt)  -> per-lane softmax
// O^T = V^T·P^T (col=q=l16, row=d=quad*4+r+16nt)
__global__ __launch_bounds__(256)
void attn(const unsigned short* __restrict__ q,
          const unsigned short* __restrict__ k,
          const unsigned short* __restrict__ vt_g,   // [b,h,64,S]
          const int* __restrict__ mask,
          unsigned short* __restrict__ ctx)          // [b,S,1024] bf16
{
    __shared__ __align__(16) unsigned short kt[64 * 88];   // [key][d]
    __shared__ __align__(16) unsigned short vt[64 * 88];   // [d][key]
    __shared__ __align__(16) __bf16 pt[4][16 * 72];        // per-wave P^T as [q][key], stride 72
    __shared__ float mkv[64];

    const int tid  = threadIdx.x;
    const int lane = tid & 63, wv = tid >> 6;
    const int quad = lane >> 4, l16 = lane & 15;
    const int qt = blockIdx.x, h = blockIdx.y, b = blockIdx.z;
    const int bh = b * NH + h;

    // Q fragments (B-operand now; same addresses as r9's A-read)
    const int sq = qt * 64 + wv * 16 + l16;
    bf16x8 qf0 = *(const bf16x8*)&q[((long)bh * S_LEN + sq) * HD + quad * 8];
    bf16x8 qf1 = *(const bf16x8*)&q[((long)bh * S_LEN + sq) * HD + 32 + quad * 8];

    float mrun = -1e30f, lrun = 0.f;      // lane scalars: this lane owns q-row sq
    f32x4 Of[4] = {};                      // O^T[d = nt*16+quad*4+r][q = l16]

    const int r8 = tid >> 3, c8 = (tid & 7) * 8;
    __bf16* ptw = pt[wv];

    for (int k0 = 0; k0 < S_LEN; k0 += 64) {
        *(uint4*)&kt[r8 * 88 + c8]        = *(const uint4*)&k[((long)bh * S_LEN + k0 + r8) * HD + c8];
        *(uint4*)&kt[(r8 + 32) * 88 + c8] = *(const uint4*)&k[((long)bh * S_LEN + k0 + r8 + 32) * HD + c8];
        *(uint4*)&vt[r8 * 88 + c8]        = *(const uint4*)&vt_g[((long)bh * HD + r8) * S_LEN + k0 + c8];
        *(uint4*)&vt[(r8 + 32) * 88 + c8] = *(const uint4*)&vt_g[((long)bh * HD + r8 + 32) * S_LEN + k0 + c8];
        if (tid < 64) mkv[tid] = (mask[b * S_LEN + k0 + tid] == 0) ? -1e9f : 0.f;
        __syncthreads();

        // S^T tile: rows=keys, cols=q.  A = K rows, B = Q rows.
        float st[4][4];
#pragma unroll
        for (int nt = 0; nt < 4; nt++) {
            bf16x8 k0f = *(const bf16x8*)&kt[(nt * 16 + l16) * 88 + quad * 8];
            bf16x8 k1f = *(const bf16x8*)&kt[(nt * 16 + l16) * 88 + 32 + quad * 8];
            f32x4 s = {};
            s = __builtin_amdgcn_mfma_f32_16x16x32_bf16(k0f, qf0, s, 0, 0, 0);
            s = __builtin_amdgcn_mfma_f32_16x16x32_bf16(k1f, qf1, s, 0, 0, 0);
            const float4 mv = *(const float4*)&mkv[nt * 16 + quad * 4];
#pragma unroll
            for (int r = 0; r < 4; r++) st[nt][r] = s[r] * 0.125f + (&mv.x)[r];
        }

        // per-lane online softmax over this lane's q-row (keys split across quads)
        float mx = st[0][0];
#pragma unroll
        for (int nt = 0; nt < 4; nt++)
#pragma unroll
            for (int r = 0; r < 4; r++) mx = fmaxf(mx, st[nt][r]);
        mx = fmaxf(mx, __shfl_xor(mx, 16, 64));
        mx = fmaxf(mx, __shfl_xor(mx, 32, 64));
        const float mn = fmaxf(mrun, mx);
        const float alpha = __expf(mrun - mn);
        float pr[4][4];
        float rs = 0.f;
#pragma unroll
        for (int nt = 0; nt < 4; nt++)
#pragma unroll
            for (int r = 0; r < 4; r++) {
                const float p = __expf(st[nt][r] - mn);
                pr[nt][r] = p; rs += p;
            }
        rs += __shfl_xor(rs, 16, 64);
        rs += __shfl_xor(rs, 32, 64);
        lrun = lrun * alpha + rs;
        mrun = mn;
#pragma unroll
        for (int nt = 0; nt < 4; nt++) Of[nt] *= alpha;

        // P^T (C-layout) -> per-wave LDS [q][key] via packed b64 writes
#pragma unroll
        for (int nt = 0; nt < 4; nt++) {
            const unsigned long long lo = pk2(pr[nt][0], pr[nt][1]);
            const unsigned long long hi = pk2(pr[nt][2], pr[nt][3]);
            *(unsigned long long*)&ptw[l16 * 72 + nt * 16 + quad * 4] = lo | (hi << 32);
        }
        asm volatile("" ::: "memory");

        // O^T += V^T · P^T   (A = vt rows = d, B = ptw rows = q)
#pragma unroll
        for (int ks = 0; ks < 2; ks++) {
            bf16x8 bp = *(const bf16x8*)&ptw[l16 * 72 + ks * 32 + quad * 8];
#pragma unroll
            for (int nt = 0; nt < 4; nt++) {
                bf16x8 av = *(const bf16x8*)&vt[(nt * 16 + l16) * 88 + ks * 32 + quad * 8];
                Of[nt] = __builtin_amdgcn_mfma_f32_16x16x32_bf16(av, bp, Of[nt], 0, 0, 0);
            }
        }
        __syncthreads();
    }

    const float inv = 1.f / lrun;
#pragma unroll
    for (int nt = 0; nt < 4; nt++) {
        const unsigned int lo = pk2(Of[nt][0] * inv, Of[nt][1] * inv);
        const unsigned int hi = pk2(Of[nt][2] * inv, Of[nt][3] * inv);
        uint2 o; o.x = lo; o.y = hi;
        *(uint2*)&ctx[((long)b * S_LEN + sq) * HID + h * HD + nt * 16 + quad * 4] = o;
    }
}

extern "C" void kernel_launch(void* const* d_in, const int* in_sizes, int n_in,
                              void* d_out, int out_size, void* d_ws, size_t ws_size,
                              hipStream_t stream) {
    float* outp = (float*)d_out;

    const float* x = nullptr; const int* mask = nullptr;
    const float* qkv_w = nullptr; const float* qkv_b = nullptr;
    const float* out_w = nullptr; const float* out_b = nullptr;
    for (int i = 0; i < n_in; i++) {
        switch (in_sizes[i]) {
            case 4194304: x     = (const float*)d_in[i]; break;
            case 4096:    mask  = (const int*)d_in[i];   break;
            case 3145728: qkv_w = (const float*)d_in[i]; break;
            case 3072:    qkv_b = (const float*)d_in[i]; break;
            case 1048576: out_w = (const float*)d_in[i]; break;
            case 1024:    out_b = (const float*)d_in[i]; break;
            default: break;
        }
    }
    if (!x || !mask || !qkv_w || !qkv_b || !out_w || !out_b) {
        fill_constf<<<256, 256, 0, stream>>>(outp, (long)out_size, 1000.0f);
        return;
    }

    const size_t per = (size_t)BATCH * NH * S_LEN * HD;   // 4,194,304
    const size_t nx  = (size_t)BATCH * S_LEN * HID;       // 4,194,304
    const size_t nqw = (size_t)3 * HID * HID;             // 3,145,728
    const size_t now = (size_t)HID * HID;                 // 1,048,576
    if (ws_size < 4 * per * sizeof(unsigned short)) {
        fill_constf<<<256, 256, 0, stream>>>(outp, (long)out_size, 2000.0f);
        return;
    }

    unsigned short* wsq = (unsigned short*)d_ws;
    unsigned short* wsk = wsq + per;
    unsigned short* wsv = wsk + per;   // V^T [b,h,64,S]
    unsigned short* wsc = wsv + per;   // ctx [b,S,1024] bf16

    const size_t need_pre = (4 * per + nx + nqw + now) * sizeof(unsigned short);
    if (ws_size >= need_pre) {
        // pre-convert path: bulk fp32->bf16 once, GEMMs stage pure bf16
        unsigned short* xb  = wsc + per;
        unsigned short* qwb = xb + nx;
        unsigned short* owb = qwb + nqw;
        cvt_bf16<<<1024, 256, 0, stream>>>(x, xb, (long)(nx / 8));
        cvt_bf16<<<1024, 256, 0, stream>>>(qkv_w, qwb, (long)(nqw / 8));
        cvt_bf16<<<512, 256, 0, stream>>>(out_w, owb, (long)(now / 8));
        fused_gemm<false, false><<<dim3(3 * HID / 128, BATCH * S_LEN / 128), 256, 0, stream>>>(
            xb, qwb, qkv_b, wsq, wsk, wsv, nullptr, 0);
        attn<<<dim3(S_LEN / 64, NH, BATCH), 256, 0, stream>>>(wsq, wsk, wsv, mask, wsc);
        fused_gemm<false, false><<<dim3(HID / 128, BATCH * S_LEN / 128), 256, 0, stream>>>(
            wsc, owb, out_b, nullptr, nullptr, nullptr, outp, 1);
    } else {
        // fused-convert fallback (r9 structure, faster pk2)
        fused_gemm<true, true><<<dim3(3 * HID / 128, BATCH * S_LEN / 128), 256, 0, stream>>>(
            x, qkv_w, qkv_b, wsq, wsk, wsv, nullptr, 0);
        attn<<<dim3(S_LEN / 64, NH, BATCH), 256, 0, stream>>>(wsq, wsk, wsv, mask, wsc);
        fused_gemm<false, true><<<dim3(HID / 128, BATCH * S_LEN / 128), 256, 0, stream>>>(
            wsc, out_w, out_b, nullptr, nullptr, nullptr, outp, 1);
    }
}

// Round 11
// 250.339 us; speedup vs baseline: 1.3167x; 1.0694x over previous
//
#include <hip/hip_runtime.h>
#include <hip/hip_bf16.h>

#define S_LEN 2048
#define NH    16
#define HD    64
#define HID   1024
#define BATCH 2
#define STK   72   // kt/vt LDS stride (shorts) = 144B: 16B-aligned, clean 36-bank rotation

typedef __bf16 bf16x8 __attribute__((ext_vector_type(8)));
typedef float  f32x4  __attribute__((ext_vector_type(4)));

__device__ __forceinline__ unsigned int pk2(float lo, float hi) {
    union { __hip_bfloat162 h; unsigned int u; } c;
    c.h = __float22bfloat162_rn(make_float2(lo, hi));   // v_cvt_pk_bf16_f32
    return c.u;
}
__device__ __forceinline__ uint4 pk8(float4 a, float4 b) {
    uint4 o;
    o.x = pk2(a.x, a.y); o.y = pk2(a.z, a.w);
    o.z = pk2(b.x, b.y); o.w = pk2(b.z, b.w);
    return o;
}
__device__ __forceinline__ float exp2_hw(float x) {
    float r; asm("v_exp_f32 %0, %1" : "=v"(r) : "v"(x)); return r;
}
// async global->LDS, 16B/lane. Dest = wave-uniform base + lane*16 (m97/m104 semantics).
__device__ __forceinline__ void gll16(const unsigned short* g, unsigned short* l) {
    __builtin_amdgcn_global_load_lds(
        (const __attribute__((address_space(1))) void*)g,
        (__attribute__((address_space(3))) void*)l, 16, 0, 0);
}

__global__ __launch_bounds__(256)
void fill_constf(float* __restrict__ out, long n, float v) {
    long i = (long)blockIdx.x * 256 + threadIdx.x;
    const long stride = (long)gridDim.x * 256;
    for (; i < n; i += stride) out[i] = v;
}

// fp32 -> bf16 bulk convert, 8 elems/iter.
__global__ __launch_bounds__(256)
void cvt_bf16(const float* __restrict__ src, unsigned short* __restrict__ dst, long n8) {
    long t = (long)blockIdx.x * 256 + threadIdx.x;
    const long stride = (long)gridDim.x * 256;
    for (; t < n8; t += stride) {
        const float4 a = *(const float4*)(src + t * 8);
        const float4 b = *(const float4*)(src + t * 8 + 4);
        *(uint4*)(dst + t * 8) = pk8(a, b);
    }
}
// two-tensor variant (x and qkv_w in one launch)
__global__ __launch_bounds__(256)
void cvt2_bf16(const float* __restrict__ s0, unsigned short* __restrict__ d0, long n0,
               const float* __restrict__ s1, unsigned short* __restrict__ d1, long n1) {
    long t = (long)blockIdx.x * 256 + threadIdx.x;
    const long stride = (long)gridDim.x * 256;
    for (; t < n0 + n1; t += stride) {
        const float* s; unsigned short* d; long i;
        if (t < n0) { s = s0; d = d0; i = t; } else { s = s1; d = d1; i = t - n0; }
        const float4 a = *(const float4*)(s + i * 8);
        const float4 b = *(const float4*)(s + i * 8 + 4);
        *(uint4*)(d + i * 8) = pk8(a, b);
    }
}

// C = A[M,K]·W[N,K]^T + bias, A/W bf16, m97-style global_load_lds staging.
// mode 0: scatter bf16 -> q/k/v^T (N=3072); mode 1: fp32 row-major store (N=1024).
__global__ __launch_bounds__(256)
void gemm_bf16(const unsigned short* __restrict__ A,
               const unsigned short* __restrict__ W,
               const float* __restrict__ bias,
               unsigned short* __restrict__ o0,
               unsigned short* __restrict__ o1,
               unsigned short* __restrict__ o2,
               float* __restrict__ of,
               int mode)
{
    __shared__ __align__(16) unsigned short lA[128 * 32];   // contiguous: required by gll
    __shared__ __align__(16) unsigned short lB[128 * 32];
    const int tid  = threadIdx.x;
    const int lane = tid & 63, wv = tid >> 6;
    const int quad = lane >> 4, l16 = lane & 15;
    const int wm = (wv & 1) * 64, wn = (wv >> 1) * 64;
    const int m0 = blockIdx.y * 128, n0 = blockIdx.x * 128;

    f32x4 acc[4][4] = {};

    // staging map: wave wv issues 2 gll per matrix; lane covers (row, 8-elem chunk)
    // LDS byte (wv*2+j)*1024 + lane*16  ->  row = (wv*2+j)*16 + lane/4, chunk = lane&3
    const int srow0 = wv * 32 + (lane >> 2);
    const int srow1 = srow0 + 16;
    const int sc    = (lane & 3) * 8;
    const unsigned short* pa0 = A + (long)(m0 + srow0) * HID + sc;
    const unsigned short* pa1 = A + (long)(m0 + srow1) * HID + sc;
    const unsigned short* pb0 = W + (long)(n0 + srow0) * HID + sc;
    const unsigned short* pb1 = W + (long)(n0 + srow1) * HID + sc;
    unsigned short* la0 = &lA[(wv * 2 + 0) * 512];
    unsigned short* la1 = &lA[(wv * 2 + 1) * 512];
    unsigned short* lb0 = &lB[(wv * 2 + 0) * 512];
    unsigned short* lb1 = &lB[(wv * 2 + 1) * 512];

    for (int k0 = 0; k0 < HID; k0 += 32) {
        gll16(pa0 + k0, la0);
        gll16(pa1 + k0, la1);
        gll16(pb0 + k0, lb0);
        gll16(pb1 + k0, lb1);
        __syncthreads();   // compiler drains vmcnt(0) before s_barrier

        bf16x8 af[4], bfr[4];
#pragma unroll
        for (int mt = 0; mt < 4; mt++)
            af[mt] = *(const bf16x8*)&lA[(wm + mt * 16 + l16) * 32 + quad * 8];
#pragma unroll
        for (int nt = 0; nt < 4; nt++)
            bfr[nt] = *(const bf16x8*)&lB[(wn + nt * 16 + l16) * 32 + quad * 8];
#pragma unroll
        for (int mt = 0; mt < 4; mt++)
#pragma unroll
            for (int nt = 0; nt < 4; nt++)
                acc[mt][nt] = __builtin_amdgcn_mfma_f32_16x16x32_bf16(
                    af[mt], bfr[nt], acc[mt][nt], 0, 0, 0);
        __syncthreads();
    }

    if (mode == 0) {
#pragma unroll
        for (int nt = 0; nt < 4; nt++) {
            const int n = n0 + wn + nt * 16 + l16;
            const float bv = bias[n];
            const int part = n >> 10, f = n & 1023, h = f >> 6, d = f & 63;
#pragma unroll
            for (int mt = 0; mt < 4; mt++) {
                const int mbase = m0 + wm + mt * 16 + quad * 4;
#pragma unroll
                for (int r = 0; r < 4; r++) {
                    const int m = mbase + r;
                    const int b = m >> 11, s = m & 2047;
                    union { __hip_bfloat16 h; unsigned short u; } cv;
                    cv.h = __float2bfloat16(acc[mt][nt][r] + bv);
                    const int bh = b * NH + h;
                    if (part == 0)      o0[((long)bh * S_LEN + s) * HD + d] = cv.u;
                    else if (part == 1) o1[((long)bh * S_LEN + s) * HD + d] = cv.u;
                    else                o2[((long)bh * HD + d) * S_LEN + s] = cv.u;
                }
            }
        }
    } else {
#pragma unroll
        for (int nt = 0; nt < 4; nt++) {
            const int n = n0 + wn + nt * 16 + l16;
            const float bv = bias[n];
#pragma unroll
            for (int mt = 0; mt < 4; mt++) {
                const int mbase = m0 + wm + mt * 16 + quad * 4;
#pragma unroll
                for (int r = 0; r < 4; r++)
                    of[(long)(mbase + r) * HID + n] = acc[mt][nt][r] + bv;
            }
        }
    }
}

// Flash attention, S^T formulation, exp2-domain softmax.
__global__ __launch_bounds__(256)
void attn(const unsigned short* __restrict__ q,
          const unsigned short* __restrict__ k,
          const unsigned short* __restrict__ vt_g,   // [b,h,64,S]
          const int* __restrict__ mask,
          unsigned short* __restrict__ ctx)          // [b,S,1024] bf16
{
    __shared__ __align__(16) unsigned short kt[64 * STK];
    __shared__ __align__(16) unsigned short vt[64 * STK];
    __shared__ __align__(16) __bf16 pt[4][16 * 72];
    __shared__ float mkv[64];

    const int tid  = threadIdx.x;
    const int lane = tid & 63, wv = tid >> 6;
    const int quad = lane >> 4, l16 = lane & 15;
    const int qt = blockIdx.x, h = blockIdx.y, b = blockIdx.z;
    const int bh = b * NH + h;
    const float SC = 0.18033688f;   // 0.125 * log2(e): softmax in exp2 domain

    const int sq = qt * 64 + wv * 16 + l16;
    bf16x8 qf0 = *(const bf16x8*)&q[((long)bh * S_LEN + sq) * HD + quad * 8];
    bf16x8 qf1 = *(const bf16x8*)&q[((long)bh * S_LEN + sq) * HD + 32 + quad * 8];

    float mrun = -1e30f, lrun = 0.f;
    f32x4 Of[4] = {};

    const int r8 = tid >> 3, c8 = (tid & 7) * 8;
    __bf16* ptw = pt[wv];

    for (int k0 = 0; k0 < S_LEN; k0 += 64) {
        *(uint4*)&kt[r8 * STK + c8]        = *(const uint4*)&k[((long)bh * S_LEN + k0 + r8) * HD + c8];
        *(uint4*)&kt[(r8 + 32) * STK + c8] = *(const uint4*)&k[((long)bh * S_LEN + k0 + r8 + 32) * HD + c8];
        *(uint4*)&vt[r8 * STK + c8]        = *(const uint4*)&vt_g[((long)bh * HD + r8) * S_LEN + k0 + c8];
        *(uint4*)&vt[(r8 + 32) * STK + c8] = *(const uint4*)&vt_g[((long)bh * HD + r8 + 32) * S_LEN + k0 + c8];
        if (tid < 64) mkv[tid] = (mask[b * S_LEN + k0 + tid] == 0) ? -1e9f : 0.f;
        __syncthreads();

        float st[4][4];
#pragma unroll
        for (int nt = 0; nt < 4; nt++) {
            bf16x8 k0f = *(const bf16x8*)&kt[(nt * 16 + l16) * STK + quad * 8];
            bf16x8 k1f = *(const bf16x8*)&kt[(nt * 16 + l16) * STK + 32 + quad * 8];
            f32x4 s = {};
            s = __builtin_amdgcn_mfma_f32_16x16x32_bf16(k0f, qf0, s, 0, 0, 0);
            s = __builtin_amdgcn_mfma_f32_16x16x32_bf16(k1f, qf1, s, 0, 0, 0);
            const float4 mv = *(const float4*)&mkv[nt * 16 + quad * 4];
#pragma unroll
            for (int r = 0; r < 4; r++) st[nt][r] = fmaf(s[r], SC, (&mv.x)[r]);
        }

        float mx = st[0][0];
#pragma unroll
        for (int nt = 0; nt < 4; nt++)
#pragma unroll
            for (int r = 0; r < 4; r++) mx = fmaxf(mx, st[nt][r]);
        mx = fmaxf(mx, __shfl_xor(mx, 16, 64));
        mx = fmaxf(mx, __shfl_xor(mx, 32, 64));
        const float mn = fmaxf(mrun, mx);
        const float alpha = exp2_hw(mrun - mn);   // consumed later (hazard distance)
        float pr[4][4];
#pragma unroll
        for (int nt = 0; nt < 4; nt++)
#pragma unroll
            for (int r = 0; r < 4; r++) pr[nt][r] = exp2_hw(st[nt][r] - mn);
        float rs = 0.f;
#pragma unroll
        for (int nt = 0; nt < 4; nt++)
#pragma unroll
            for (int r = 0; r < 4; r++) rs += pr[nt][r];
        rs += __shfl_xor(rs, 16, 64);
        rs += __shfl_xor(rs, 32, 64);
        lrun = lrun * alpha + rs;
        mrun = mn;

#pragma unroll
        for (int nt = 0; nt < 4; nt++) {
            const unsigned long long lo = pk2(pr[nt][0], pr[nt][1]);
            const unsigned long long hi = pk2(pr[nt][2], pr[nt][3]);
            *(unsigned long long*)&ptw[l16 * 72 + nt * 16 + quad * 4] = lo | (hi << 32);
        }
        asm volatile("" ::: "memory");

#pragma unroll
        for (int nt = 0; nt < 4; nt++) Of[nt] *= alpha;

#pragma unroll
        for (int ks = 0; ks < 2; ks++) {
            bf16x8 bp = *(const bf16x8*)&ptw[l16 * 72 + ks * 32 + quad * 8];
#pragma unroll
            for (int nt = 0; nt < 4; nt++) {
                bf16x8 av = *(const bf16x8*)&vt[(nt * 16 + l16) * STK + ks * 32 + quad * 8];
                Of[nt] = __builtin_amdgcn_mfma_f32_16x16x32_bf16(av, bp, Of[nt], 0, 0, 0);
            }
        }
        __syncthreads();
    }

    const float inv = 1.f / lrun;
#pragma unroll
    for (int nt = 0; nt < 4; nt++) {
        uint2 o;
        o.x = pk2(Of[nt][0] * inv, Of[nt][1] * inv);
        o.y = pk2(Of[nt][2] * inv, Of[nt][3] * inv);
        *(uint2*)&ctx[((long)b * S_LEN + sq) * HID + h * HD + nt * 16 + quad * 4] = o;
    }
}

extern "C" void kernel_launch(void* const* d_in, const int* in_sizes, int n_in,
                              void* d_out, int out_size, void* d_ws, size_t ws_size,
                              hipStream_t stream) {
    float* outp = (float*)d_out;

    const float* x = nullptr; const int* mask = nullptr;
    const float* qkv_w = nullptr; const float* qkv_b = nullptr;
    const float* out_w = nullptr; const float* out_b = nullptr;
    for (int i = 0; i < n_in; i++) {
        switch (in_sizes[i]) {
            case 4194304: x     = (const float*)d_in[i]; break;
            case 4096:    mask  = (const int*)d_in[i];   break;
            case 3145728: qkv_w = (const float*)d_in[i]; break;
            case 3072:    qkv_b = (const float*)d_in[i]; break;
            case 1048576: out_w = (const float*)d_in[i]; break;
            case 1024:    out_b = (const float*)d_in[i]; break;
            default: break;
        }
    }
    if (!x || !mask || !qkv_w || !qkv_b || !out_w || !out_b) {
        fill_constf<<<256, 256, 0, stream>>>(outp, (long)out_size, 1000.0f);
        return;
    }

    const size_t per = (size_t)BATCH * NH * S_LEN * HD;   // 4,194,304 elements
    const size_t nx  = (size_t)BATCH * S_LEN * HID;
    const size_t nqw = (size_t)3 * HID * HID;
    const size_t now = (size_t)HID * HID;
    if (ws_size < 4 * per * sizeof(unsigned short)) {
        fill_constf<<<256, 256, 0, stream>>>(outp, (long)out_size, 2000.0f);
        return;
    }

    unsigned short* wsq = (unsigned short*)d_ws;
    unsigned short* wsk = wsq + per;
    unsigned short* wsv = wsk + per;             // V^T [b,h,64,S]
    unsigned short* wsc = wsv + per;             // phase 1: xb (x as bf16); phase 2: ctx
    unsigned short* xb  = wsc;                   // alias — dead once attn writes ctx
    unsigned short* qwb = (unsigned short*)d_out; // scratch inside output buffer (6.3 of 16.8 MB)
    unsigned short* owb = wsq;                   // q is dead after attn

    cvt2_bf16<<<1024, 256, 0, stream>>>(x, xb, (long)(nx / 8), qkv_w, qwb, (long)(nqw / 8));
    gemm_bf16<<<dim3(3 * HID / 128, BATCH * S_LEN / 128), 256, 0, stream>>>(
        xb, qwb, qkv_b, wsq, wsk, wsv, nullptr, 0);
    attn<<<dim3(S_LEN / 64, NH, BATCH), 256, 0, stream>>>(wsq, wsk, wsv, mask, wsc);
    cvt_bf16<<<512, 256, 0, stream>>>(out_w, owb, (long)(now / 8));
    gemm_bf16<<<dim3(HID / 128, BATCH * S_LEN / 128), 256, 0, stream>>>(
        wsc, owb, out_b, nullptr, nullptr, nullptr, outp, 1);
}

// Round 13
// 235.525 us; speedup vs baseline: 1.3995x; 1.0629x over previous
//
#include <hip/hip_runtime.h>
#include <hip/hip_bf16.h>

#define S_LEN 2048
#define NH    16
#define HD    64
#define HID   1024
#define BATCH 2
#define STK   72   // kt/vt LDS stride in shorts (144B rows, 16B aligned)

typedef __bf16 bf16x8 __attribute__((ext_vector_type(8)));
typedef float  f32x4  __attribute__((ext_vector_type(4)));

__device__ __forceinline__ unsigned int pk2(float lo, float hi) {
    union { __hip_bfloat162 h; unsigned int u; } c;
    c.h = __float22bfloat162_rn(make_float2(lo, hi));   // v_cvt_pk_bf16_f32
    return c.u;
}
__device__ __forceinline__ uint4 pk8(float4 a, float4 b) {
    uint4 o;
    o.x = pk2(a.x, a.y); o.y = pk2(a.z, a.w);
    o.z = pk2(b.x, b.y); o.w = pk2(b.z, b.w);
    return o;
}
__device__ __forceinline__ float exp2_hw(float x) {
    float r; asm("v_exp_f32 %0, %1" : "=v"(r) : "v"(x)); return r;
}
__device__ __forceinline__ void gll16(const unsigned short* g, unsigned short* l) {
    __builtin_amdgcn_global_load_lds(
        (const __attribute__((address_space(1))) void*)g,
        (__attribute__((address_space(3))) void*)l, 16, 0, 0);
}

__global__ __launch_bounds__(256)
void fill_constf(float* __restrict__ out, long n, float v) {
    long i = (long)blockIdx.x * 256 + threadIdx.x;
    const long stride = (long)gridDim.x * 256;
    for (; i < n; i += stride) out[i] = v;
}

// fp32 -> bf16 bulk convert, 8 elems/iter.
__global__ __launch_bounds__(256)
void cvt_bf16(const float* __restrict__ src, unsigned short* __restrict__ dst, long n8) {
    long t = (long)blockIdx.x * 256 + threadIdx.x;
    const long stride = (long)gridDim.x * 256;
    for (; t < n8; t += stride) {
        const float4 a = *(const float4*)(src + t * 8);
        const float4 b = *(const float4*)(src + t * 8 + 4);
        *(uint4*)(dst + t * 8) = pk8(a, b);
    }
}
// two-tensor variant (x and qkv_w in one launch)
__global__ __launch_bounds__(256)
void cvt2_bf16(const float* __restrict__ s0, unsigned short* __restrict__ d0, long n0,
               const float* __restrict__ s1, unsigned short* __restrict__ d1, long n1) {
    long t = (long)blockIdx.x * 256 + threadIdx.x;
    const long stride = (long)gridDim.x * 256;
    for (; t < n0 + n1; t += stride) {
        const float* s; unsigned short* d; long i;
        if (t < n0) { s = s0; d = d0; i = t; } else { s = s1; d = d1; i = t - n0; }
        const float4 a = *(const float4*)(s + i * 8);
        const float4 b = *(const float4*)(s + i * 8 + 4);
        *(uint4*)(d + i * 8) = pk8(a, b);
    }
}

// C = A[M,K]·W[N,K]^T + bias, bf16 in, global_load_lds staging.
// mode 0: scatter bf16 -> q/k (row-scatter) and V^T (packed 8B); mode 1: fp32 store.
__global__ __launch_bounds__(256)
void gemm_bf16(const unsigned short* __restrict__ A,
               const unsigned short* __restrict__ W,
               const float* __restrict__ bias,
               unsigned short* __restrict__ o0,
               unsigned short* __restrict__ o1,
               unsigned short* __restrict__ o2,
               float* __restrict__ of,
               int mode)
{
    __shared__ __align__(16) unsigned short lA[128 * 32];
    __shared__ __align__(16) unsigned short lB[128 * 32];
    const int tid  = threadIdx.x;
    const int lane = tid & 63, wv = tid >> 6;
    const int quad = lane >> 4, l16 = lane & 15;
    const int wm = (wv & 1) * 64, wn = (wv >> 1) * 64;
    const int m0 = blockIdx.y * 128, n0 = blockIdx.x * 128;

    f32x4 acc[4][4] = {};

    const int srow0 = wv * 32 + (lane >> 2);
    const int srow1 = srow0 + 16;
    const int sc    = (lane & 3) * 8;
    const unsigned short* pa0 = A + (long)(m0 + srow0) * HID + sc;
    const unsigned short* pa1 = A + (long)(m0 + srow1) * HID + sc;
    const unsigned short* pb0 = W + (long)(n0 + srow0) * HID + sc;
    const unsigned short* pb1 = W + (long)(n0 + srow1) * HID + sc;
    unsigned short* la0 = &lA[(wv * 2 + 0) * 512];
    unsigned short* la1 = &lA[(wv * 2 + 1) * 512];
    unsigned short* lb0 = &lB[(wv * 2 + 0) * 512];
    unsigned short* lb1 = &lB[(wv * 2 + 1) * 512];

    for (int k0 = 0; k0 < HID; k0 += 32) {
        gll16(pa0 + k0, la0);
        gll16(pa1 + k0, la1);
        gll16(pb0 + k0, lb0);
        gll16(pb1 + k0, lb1);
        __syncthreads();

        bf16x8 af[4], bfr[4];
#pragma unroll
        for (int mt = 0; mt < 4; mt++)
            af[mt] = *(const bf16x8*)&lA[(wm + mt * 16 + l16) * 32 + quad * 8];
#pragma unroll
        for (int nt = 0; nt < 4; nt++)
            bfr[nt] = *(const bf16x8*)&lB[(wn + nt * 16 + l16) * 32 + quad * 8];
#pragma unroll
        for (int mt = 0; mt < 4; mt++)
#pragma unroll
            for (int nt = 0; nt < 4; nt++)
                acc[mt][nt] = __builtin_amdgcn_mfma_f32_16x16x32_bf16(
                    af[mt], bfr[nt], acc[mt][nt], 0, 0, 0);
        __syncthreads();
    }

    if (mode == 0) {
#pragma unroll
        for (int nt = 0; nt < 4; nt++) {
            const int n = n0 + wn + nt * 16 + l16;
            const float bv = bias[n];
            const int part = n >> 10, f = n & 1023, h = f >> 6, d = f & 63;
#pragma unroll
            for (int mt = 0; mt < 4; mt++) {
                const int mbase = m0 + wm + mt * 16 + quad * 4;
                const int b = mbase >> 11, s0 = mbase & 2047;
                const int bh = b * NH + h;
                if (part == 2) {
                    // V^T: 4 consecutive s per lane -> one packed 8B store
                    uint2 o;
                    o.x = pk2(acc[mt][nt][0] + bv, acc[mt][nt][1] + bv);
                    o.y = pk2(acc[mt][nt][2] + bv, acc[mt][nt][3] + bv);
                    *(uint2*)&o2[((long)bh * HD + d) * S_LEN + s0] = o;
                } else {
                    unsigned short* dst = (part == 0) ? o0 : o1;
#pragma unroll
                    for (int r = 0; r < 4; r++) {
                        union { __hip_bfloat16 h; unsigned short u; } cv;
                        cv.h = __float2bfloat16(acc[mt][nt][r] + bv);
                        dst[((long)bh * S_LEN + s0 + r) * HD + d] = cv.u;
                    }
                }
            }
        }
    } else {
#pragma unroll
        for (int nt = 0; nt < 4; nt++) {
            const int n = n0 + wn + nt * 16 + l16;
            const float bv = bias[n];
#pragma unroll
            for (int mt = 0; mt < 4; mt++) {
                const int mbase = m0 + wm + mt * 16 + quad * 4;
#pragma unroll
                for (int r = 0; r < 4; r++)
                    of[(long)(mbase + r) * HID + n] = acc[mt][nt][r] + bv;
            }
        }
    }
}

// Flash attention, S^T form, exp2 softmax. 512 threads (8 waves), q-tile 128.
// Register-prefetch double-buffered K/V staging; 2 barriers per 64-key tile.
__global__ __launch_bounds__(512)
void attn(const unsigned short* __restrict__ q,
          const unsigned short* __restrict__ k,
          const unsigned short* __restrict__ vt_g,   // [b,h,64,S]
          const int* __restrict__ mask,
          unsigned short* __restrict__ ctx)          // [b,S,1024] bf16
{
    __shared__ __align__(16) unsigned short kt[64 * STK];
    __shared__ __align__(16) unsigned short vt[64 * STK];
    __shared__ __align__(16) __bf16 pt[8][16 * 72];
    __shared__ float mkv[64];

    const int tid  = threadIdx.x;
    const int lane = tid & 63, wv = tid >> 6;          // wv 0..7
    const int quad = lane >> 4, l16 = lane & 15;
    const int qt = blockIdx.x, h = blockIdx.y, b = blockIdx.z;
    const int bh = b * NH + h;
    const float SC = 0.18033688f;   // 0.125 * log2(e)

    const int sq = qt * 128 + wv * 16 + l16;
    bf16x8 qf0 = *(const bf16x8*)&q[((long)bh * S_LEN + sq) * HD + quad * 8];
    bf16x8 qf1 = *(const bf16x8*)&q[((long)bh * S_LEN + sq) * HD + 32 + quad * 8];

    float mrun = -1e30f, lrun = 0.f;
    f32x4 Of[4] = {};

    // staging: 512 threads cover 64 rows x 8 chunks, one uint4 each per matrix
    const int sr = tid >> 3, sc8 = (tid & 7) * 8;
    const unsigned short* kg = k    + ((long)bh * S_LEN + sr) * HD + sc8;
    const unsigned short* vg = vt_g + ((long)bh * HD + sr) * S_LEN + sc8;
    __bf16* ptw = pt[wv];

    // prefetch tile 0
    uint4 rk = *(const uint4*)(kg);
    uint4 rv = *(const uint4*)(vg);
    float rm = 0.f;
    if (tid < 64) rm = (mask[b * S_LEN + tid] == 0) ? -1e9f : 0.f;

    for (int k0 = 0; k0 < S_LEN; k0 += 64) {
        *(uint4*)&kt[sr * STK + sc8] = rk;
        *(uint4*)&vt[sr * STK + sc8] = rv;
        if (tid < 64) mkv[tid] = rm;
        if (k0 + 64 < S_LEN) {
            rk = *(const uint4*)(kg + (long)(k0 + 64) * HD);
            rv = *(const uint4*)(vg + (k0 + 64));
            if (tid < 64) rm = (mask[b * S_LEN + k0 + 64 + tid] == 0) ? -1e9f : 0.f;
        }
        __syncthreads();

        float st[4][4];
#pragma unroll
        for (int nt = 0; nt < 4; nt++) {
            bf16x8 k0f = *(const bf16x8*)&kt[(nt * 16 + l16) * STK + quad * 8];
            bf16x8 k1f = *(const bf16x8*)&kt[(nt * 16 + l16) * STK + 32 + quad * 8];
            f32x4 s = {};
            s = __builtin_amdgcn_mfma_f32_16x16x32_bf16(k0f, qf0, s, 0, 0, 0);
            s = __builtin_amdgcn_mfma_f32_16x16x32_bf16(k1f, qf1, s, 0, 0, 0);
            const float4 mv = *(const float4*)&mkv[nt * 16 + quad * 4];
#pragma unroll
            for (int r = 0; r < 4; r++) st[nt][r] = fmaf(s[r], SC, (&mv.x)[r]);
        }

        float mx = st[0][0];
#pragma unroll
        for (int nt = 0; nt < 4; nt++)
#pragma unroll
            for (int r = 0; r < 4; r++) mx = fmaxf(mx, st[nt][r]);
        mx = fmaxf(mx, __shfl_xor(mx, 16, 64));
        mx = fmaxf(mx, __shfl_xor(mx, 32, 64));
        const float mn = fmaxf(mrun, mx);
        const float alpha = exp2_hw(mrun - mn);
        float pr[4][4];
#pragma unroll
        for (int nt = 0; nt < 4; nt++)
#pragma unroll
            for (int r = 0; r < 4; r++) pr[nt][r] = exp2_hw(st[nt][r] - mn);
        float rs = 0.f;
#pragma unroll
        for (int nt = 0; nt < 4; nt++)
#pragma unroll
            for (int r = 0; r < 4; r++) rs += pr[nt][r];
        rs += __shfl_xor(rs, 16, 64);
        rs += __shfl_xor(rs, 32, 64);
        lrun = lrun * alpha + rs;
        mrun = mn;

#pragma unroll
        for (int nt = 0; nt < 4; nt++) {
            const unsigned long long lo = pk2(pr[nt][0], pr[nt][1]);
            const unsigned long long hi = pk2(pr[nt][2], pr[nt][3]);
            *(unsigned long long*)&ptw[l16 * 72 + nt * 16 + quad * 4] = lo | (hi << 32);
        }
        asm volatile("" ::: "memory");

#pragma unroll
        for (int nt = 0; nt < 4; nt++) Of[nt] *= alpha;

#pragma unroll
        for (int ks = 0; ks < 2; ks++) {
            bf16x8 bp = *(const bf16x8*)&ptw[l16 * 72 + ks * 32 + quad * 8];
#pragma unroll
            for (int nt = 0; nt < 4; nt++) {
                bf16x8 av = *(const bf16x8*)&vt[(nt * 16 + l16) * STK + ks * 32 + quad * 8];
                Of[nt] = __builtin_amdgcn_mfma_f32_16x16x32_bf16(av, bp, Of[nt], 0, 0, 0);
            }
        }
        __syncthreads();
    }

    const float inv = 1.f / lrun;
#pragma unroll
    for (int nt = 0; nt < 4; nt++) {
        uint2 o;
        o.x = pk2(Of[nt][0] * inv, Of[nt][1] * inv);
        o.y = pk2(Of[nt][2] * inv, Of[nt][3] * inv);
        *(uint2*)&ctx[((long)b * S_LEN + sq) * HID + h * HD + nt * 16 + quad * 4] = o;
    }
}

extern "C" void kernel_launch(void* const* d_in, const int* in_sizes, int n_in,
                              void* d_out, int out_size, void* d_ws, size_t ws_size,
                              hipStream_t stream) {
    float* outp = (float*)d_out;

    const float* x = nullptr; const int* mask = nullptr;
    const float* qkv_w = nullptr; const float* qkv_b = nullptr;
    const float* out_w = nullptr; const float* out_b = nullptr;
    for (int i = 0; i < n_in; i++) {
        switch (in_sizes[i]) {
            case 4194304: x     = (const float*)d_in[i]; break;
            case 4096:    mask  = (const int*)d_in[i];   break;
            case 3145728: qkv_w = (const float*)d_in[i]; break;
            case 3072:    qkv_b = (const float*)d_in[i]; break;
            case 1048576: out_w = (const float*)d_in[i]; break;
            case 1024:    out_b = (const float*)d_in[i]; break;
            default: break;
        }
    }
    if (!x || !mask || !qkv_w || !qkv_b || !out_w || !out_b) {
        fill_constf<<<256, 256, 0, stream>>>(outp, (long)out_size, 1000.0f);
        return;
    }

    const size_t per = (size_t)BATCH * NH * S_LEN * HD;   // 4,194,304
    const size_t nx  = (size_t)BATCH * S_LEN * HID;
    const size_t nqw = (size_t)3 * HID * HID;
    const size_t now = (size_t)HID * HID;
    if (ws_size < 4 * per * sizeof(unsigned short)) {
        fill_constf<<<256, 256, 0, stream>>>(outp, (long)out_size, 2000.0f);
        return;
    }

    // Aliasing discipline (no buffer read+written in the same kernel):
    //   xb  = wsc : dead after gemm1; attn overwrites with ctx
    //   qwb = d_out[0,6.3MB) : dead after gemm1; gemm2 overwrites with output
    //   owb = wsq : written AFTER attn (q dead), read only by gemm2
    unsigned short* wsq = (unsigned short*)d_ws;
    unsigned short* wsk = wsq + per;
    unsigned short* wsv = wsk + per;               // V^T [b,h,64,S]
    unsigned short* wsc = wsv + per;               // phase 1: xb; phase 2: ctx
    unsigned short* xb  = wsc;
    unsigned short* qwb = (unsigned short*)d_out;
    unsigned short* owb = wsq;

    cvt2_bf16<<<1024, 256, 0, stream>>>(x, xb, (long)(nx / 8), qkv_w, qwb, (long)(nqw / 8));
    gemm_bf16<<<dim3(3 * HID / 128, BATCH * S_LEN / 128), 256, 0, stream>>>(
        xb, qwb, qkv_b, wsq, wsk, wsv, nullptr, 0);
    attn<<<dim3(S_LEN / 128, NH, BATCH), 512, 0, stream>>>(wsq, wsk, wsv, mask, wsc);
    cvt_bf16<<<512, 256, 0, stream>>>(out_w, owb, (long)(now / 8));
    gemm_bf16<<<dim3(HID / 128, BATCH * S_LEN / 128), 256, 0, stream>>>(
        wsc, owb, out_b, nullptr, nullptr, nullptr, outp, 1);
}